// Round 7
// baseline (584.836 us; speedup 1.0000x reference)
//
#include <hip/hip_runtime.h>

#define NN 100000
#define NE 3200000
#define NF 512
#define ND 64
#define NC 10

#define NBUCK 196         // coarse buckets: dst>>9  (99999>>9 = 195)
#define NPB 500           // partition blocks
#define EPB 6400          // edges per partition block (NE/NPB)

// workspace layout (4-byte elements)
#define OFF_H      0          // NN*ND  h' = dis*(x @ W1eff); buck[] aliases (NE int2)
#define OFF_DIS    6400000    // NN     deg^-1/2 (written by bucket_sort)
#define OFF_W1     6500000    // NF*ND floats = 128KB: B-fragment array (bf16 hi/lo)
#define OFF_GH     6533408    // NBUCK*NPB = 98000 ints: per-(bin,block) histogram
#define OFF_RP     6633408    // NN+1   int CSR rowptr
#define OFF_BSUM   6733409    // 512 ints: T at +0, TS (197) at +256
#define OFF_EDGE   6733922    // NE int2 {src, bits(w)}  (8B-aligned)
#define OFF_W2F    13133922   // 1024 floats: W2eff bf16 hi/lo frags (64x16, zero-pad)
// total = 13,134,946 * 4B = 52.54 MB

typedef __attribute__((ext_vector_type(8))) short v8s;   // 8 bf16 = 4 VGPRs
typedef __attribute__((ext_vector_type(4))) float v4f;

// round-to-nearest-even fp32 -> bf16 (upper 16 bits)
__device__ __forceinline__ unsigned short bf16_rne(float f) {
  unsigned int u = __float_as_uint(f);
  return (unsigned short)((u + 0x7fffu + ((u >> 16) & 1u)) >> 16);
}

// W1eff and W2eff pre-split into bf16 hi/lo MFMA B-fragments.
// Fragment layout (MUST match the consumers):
//   k-step s = k>>5, lane-group g = (k>>3)&3, elem e = k&7, tile t = col>>4,
//   lane = (g<<4)|(col&15).  Halfword offset ((s*T+t)*64+lane)*16 + e (hi), +8 (lo).
// A and B use the SAME k->(g,e) mapping, so the MFMA result is invariant to
// the hardware's internal k-order (any consistent k-permutation cancels).
__global__ __launch_bounds__(256) void prep_kernel(
    const float* __restrict__ W1, const float* __restrict__ M1,
    const float* __restrict__ W2, const float* __restrict__ M2,
    float* __restrict__ ws) {
  const int i = blockIdx.x * 256 + threadIdx.x;   // grid = 128 (covers NF*ND)
  if (i < NF * ND) {
    const float v = W1[i] * M1[i];
    const int k = i >> 6, d = i & 63;             // i = k*ND + d
    const int s = k >> 5, g = (k >> 3) & 3, e = k & 7;
    const int t = d >> 4;
    const int lane = (g << 4) | (d & 15);
    unsigned short* bp = (unsigned short*)(ws + OFF_W1);
    const int base = ((s * 4 + t) * 64 + lane) * 16 + e;
    const unsigned short hb = bf16_rne(v);
    bp[base] = hb;
    bp[base + 8] = bf16_rne(v - __uint_as_float((unsigned int)hb << 16));
  }
  if (i < ND * 16) {                              // W2 frags, cols 10..15 zero
    const int k = i >> 4, c = i & 15;
    const float v = (c < NC) ? W2[k * NC + c] * M2[k * NC + c] : 0.0f;
    const int s = k >> 5, g = (k >> 3) & 3, e = k & 7;
    const int lane = (g << 4) | c;
    unsigned short* bp = (unsigned short*)(ws + OFF_W2F);
    const int base = (s * 64 + lane) * 16 + e;
    const unsigned short hb = bf16_rne(v);
    bp[base] = hb;
    bp[base + 8] = bf16_rne(v - __uint_as_float((unsigned int)hb << 16));
  }
}

// ---- CSR build: two-level counting sort, ZERO global atomics ----

// Pass A1: per-block coarse histogram (196 bins) via LDS atomics.
__global__ __launch_bounds__(256) void part_hist(
    const int* __restrict__ dst, int* __restrict__ GH) {
  __shared__ int hist[NBUCK];
  const int tid = threadIdx.x;
  for (int i = tid; i < NBUCK; i += 256) hist[i] = 0;
  __syncthreads();
  const int s0 = blockIdx.x * EPB;
  for (int e = s0 + tid; e < s0 + EPB; e += 256)
    atomicAdd(&hist[dst[e] >> 9], 1);
  __syncthreads();
  for (int i = tid; i < NBUCK; i += 256)
    GH[i * NPB + blockIdx.x] = hist[i];            // bin-major for the scan
}

// Pass A2: per-bin exclusive scan over the NPB block counts (in place),
// bin totals to T.
__global__ __launch_bounds__(512) void part_scan(
    int* __restrict__ GH, int* __restrict__ T) {
  __shared__ int s[512];
  const int t = threadIdx.x;
  const int b = blockIdx.x;                        // bin
  const int v = (t < NPB) ? GH[b * NPB + t] : 0;
  s[t] = v; __syncthreads();
  for (int off = 1; off < 512; off <<= 1) {
    const int a = (t >= off) ? s[t - off] : 0;
    __syncthreads();
    s[t] += a;
    __syncthreads();
  }
  if (t < NPB) GH[b * NPB + t] = s[t] - v;         // exclusive within bin
  if (t == 511) T[b] = s[511];                     // bin total
}

// Pass A3: exclusive scan of the 196 bin totals -> TS (+ sentinel TS[196]=NE).
__global__ __launch_bounds__(256) void part_scan_t(
    const int* __restrict__ T, int* __restrict__ TS) {
  __shared__ int s[256];
  const int t = threadIdx.x;
  const int v = (t < NBUCK) ? T[t] : 0;
  s[t] = v; __syncthreads();
  for (int off = 1; off < 256; off <<= 1) {
    const int a = (t >= off) ? s[t - off] : 0;
    __syncthreads();
    s[t] += a;
    __syncthreads();
  }
  if (t < NBUCK) TS[t] = s[t] - v;
  if (t == NBUCK - 1) TS[NBUCK] = s[t];            // == NE
}

// Pass A4: scatter edges into coarse-bucket runs.  Each block's range within
// each bucket is exclusive (prefix-scanned), rank via LDS cursor.
// Pack: src (17b) | fine-dst (9b) << 17;  w as float bits.
__global__ __launch_bounds__(256) void part_scatter(
    const int* __restrict__ src, const int* __restrict__ dst,
    const float* __restrict__ ew, const int* __restrict__ GH,
    const int* __restrict__ TS, int2* __restrict__ buck) {
  __shared__ int cursor[NBUCK];
  const int tid = threadIdx.x;
  for (int i = tid; i < NBUCK; i += 256)
    cursor[i] = GH[i * NPB + blockIdx.x] + TS[i];
  __syncthreads();
  const int s0 = blockIdx.x * EPB;
  for (int e = s0 + tid; e < s0 + EPB; e += 256) {
    const int d = dst[e];
    const int pos = atomicAdd(&cursor[d >> 9], 1);
    buck[pos] = make_int2(src[e] | ((d & 511) << 17), __float_as_int(ew[e]));
  }
}

// Pass B: one block per coarse bucket (512 fine bins = 512 nodes).
// Read 1: fine histogram + weighted-degree (both LDS atomics, same read).
// In-block scan -> rowptr + dis.  Read 2: scatter to final CSR edge array.
__global__ __launch_bounds__(512) void bucket_sort(
    const int* __restrict__ TS, const int2* __restrict__ buck,
    int2* __restrict__ edge, int* __restrict__ rowptr,
    float* __restrict__ dis) {
  __shared__ int hist[512];
  __shared__ float deg[512];
  __shared__ int scn[512];
  const int t = threadIdx.x;
  const int b = blockIdx.x;
  const int beg = TS[b], endd = TS[b + 1];
  hist[t] = 0; deg[t] = 0.0f;
  __syncthreads();
  for (int e = beg + t; e < endd; e += 512) {
    const int2 q = buck[e];
    const int fine = (q.x >> 17) & 511;
    atomicAdd(&hist[fine], 1);
    atomicAdd(&deg[fine], __int_as_float(q.y));
  }
  __syncthreads();
  const int sv = hist[t];
  scn[t] = sv; __syncthreads();
  for (int off = 1; off < 512; off <<= 1) {
    const int a = (t >= off) ? scn[t - off] : 0;
    __syncthreads();
    scn[t] += a;
    __syncthreads();
  }
  const int ex = scn[t] - sv;                      // exclusive
  const int node = b * 512 + t;
  if (node < NN) {
    rowptr[node] = beg + ex;
    dis[node] = rsqrtf(deg[t] + 1.0f);             // +1 = self-loop weight
  }
  if (b == NBUCK - 1 && t == 0) rowptr[NN] = endd; // == NE
  hist[t] = beg + ex;                              // reuse hist as cursor
  __syncthreads();
  for (int e = beg + t; e < endd; e += 512) {
    const int2 q = buck[e];
    const int fine = (q.x >> 17) & 511;
    const int pos = atomicAdd(&hist[fine], 1);
    edge[pos] = make_int2(q.x & 0x1FFFF, q.y);
  }
}

// h' = dis * (x @ Weff1) via bf16-split MFMA (xh*wh + xh*wl + xl*wh, fp32 acc).
// x is staged through LDS so global reads are fully line-coalesced: per
// k-step the 256-thread block loads its 128x128B x-slab (each thread one
// contiguous 64B = fully-consumed lines), ds_write_b128 with a unit-XOR
// swizzle (unit ^= row&7, 16B units within each row's 128B window).
// Write side: even 8 words/bank (min).  Fragment reads (16 lanes at 128B
// row stride, un-swizzled = 8-way conflict) land even at 8 words/bank: free.
// Double-buffered; next slab prefetched to regs under the 24 MFMAs.
// NN%32==0 so per-wave store guards suffice; staging rows clamp to NN-1
// (no early return -> uniform barriers).
// C layout (m89-verified): col = lane&15, row = (lane>>4)*4 + reg.
__global__ __launch_bounds__(256) void gemm1_kernel(
    const float* __restrict__ x, const float* __restrict__ bfrag_f,
    const float* __restrict__ dis, float* __restrict__ h) {
  __shared__ __align__(16) float xs[2][128 * 32];   // 2 x 16 KB
  const int tid  = threadIdx.x;
  const int lane = tid & 63;
  const int wid  = tid >> 6;
  const size_t brow = (size_t)blockIdx.x * 128;
  // staging assignment: thread t -> row t>>1, units (t&1)*4 .. +3
  const int srow = tid >> 1;
  const int bunit = (tid & 1) * 4;
  const int sr7 = srow & 7;
  const size_t grow = (brow + srow < NN) ? (brow + srow) : (size_t)(NN - 1);
  const float* gx = x + grow * NF + bunit * 4;
  float* wrow = &xs[0][0];                          // buffer chosen per step

  const size_t row0 = brow + (size_t)wid * 32;
  const int lr = lane & 15;               // A row / B col / C col within tile
  const int lg = lane >> 4;               // k-group
  const int crow = wid * 32;
  const v8s* bfr = (const v8s*)bfrag_f + (size_t)lane * 2;  // 32B per lane
  v4f acc[2][4];
#pragma unroll
  for (int i = 0; i < 2; ++i)
#pragma unroll
    for (int t = 0; t < 4; ++t) acc[i][t] = (v4f){0.f, 0.f, 0.f, 0.f};

  float4 pf[4];
#pragma unroll
  for (int j = 0; j < 4; ++j) pf[j] = *(const float4*)(gx + j * 4);

  for (int s = 0; s < 16; ++s) {          // k0 = s*32
    float* buf = &xs[s & 1][0];
    // stage prefetched slab (swizzled units)
    float* wr = buf + srow * 32;
#pragma unroll
    for (int j = 0; j < 4; ++j)
      *(float4*)(wr + (((bunit + j) ^ sr7) << 2)) = pf[j];
    // issue next slab's loads (fly under the MFMAs)
    if (s < 15) {
      const float* gxs = gx + (s + 1) * 32;
#pragma unroll
      for (int j = 0; j < 4; ++j) pf[j] = *(const float4*)(gxs + j * 4);
    }
    __syncthreads();
    v8s ah[2], al[2];
#pragma unroll
    for (int i = 0; i < 2; ++i) {
      const int rl = crow + i * 16 + lr;
      const float* rp = buf + rl * 32;
      const int r7 = rl & 7;
      const float4 p0 = *(const float4*)(rp + (((lg * 2) ^ r7) << 2));
      const float4 p1 = *(const float4*)(rp + (((lg * 2 + 1) ^ r7) << 2));
      const float vv[8] = {p0.x, p0.y, p0.z, p0.w, p1.x, p1.y, p1.z, p1.w};
#pragma unroll
      for (int e = 0; e < 8; ++e) {
        const unsigned short hb = bf16_rne(vv[e]);
        ah[i][e] = (short)hb;
        al[i][e] = (short)bf16_rne(vv[e] - __uint_as_float((unsigned int)hb << 16));
      }
    }
#pragma unroll
    for (int t = 0; t < 4; ++t) {
      const v8s bh = bfr[(size_t)(s * 4 + t) * 128];      // hi frag
      const v8s bl = bfr[(size_t)(s * 4 + t) * 128 + 1];  // lo frag
#pragma unroll
      for (int i = 0; i < 2; ++i) {
        acc[i][t] = __builtin_amdgcn_mfma_f32_16x16x32_bf16(ah[i], bh, acc[i][t], 0, 0, 0);
        acc[i][t] = __builtin_amdgcn_mfma_f32_16x16x32_bf16(ah[i], bl, acc[i][t], 0, 0, 0);
        acc[i][t] = __builtin_amdgcn_mfma_f32_16x16x32_bf16(al[i], bh, acc[i][t], 0, 0, 0);
      }
    }
    __syncthreads();
  }
  if (row0 < NN) {
#pragma unroll
    for (int i = 0; i < 2; ++i)
#pragma unroll
      for (int r = 0; r < 4; ++r) {
        const size_t row = row0 + i * 16 + lg * 4 + r;
        const float dv = dis[row];        // 16-lane broadcast, L1-resident
#pragma unroll
        for (int t = 0; t < 4; ++t)
          h[row * ND + t * 16 + lr] = acc[i][t][r] * dv;
      }
  }
}

// One wave per dst node.  Edge list is wave-uniform -> scalar s_load stream;
// h' already carries dis[src], so the inner loop is 1 scalar edge read +
// 1 coalesced 256B h-row load + 1 v_fmac (SGPR multiplier) per edge,
// 8 independent chains.  Epilogue: out = dis[n]*(sum + h'[n]) + b1, ReLU,
// then 4 waves stage rows in LDS and wave 0 runs the 64x10 classifier as
// one bf16-split MFMA tile.
__global__ __launch_bounds__(256) void gather_kernel(
    const int* __restrict__ rowptr, const int2* __restrict__ edge,
    const float* __restrict__ h, const float* __restrict__ dis,
    const float* __restrict__ b1, const float* __restrict__ w2f,
    const float* __restrict__ b2, float* __restrict__ out) {
  __shared__ float vls[4 * 64];
  const int lane = threadIdx.x & 63;
  const int wid  = threadIdx.x >> 6;
  const int n = blockIdx.x * 4 + wid;              // grid exact: n < NN
  const int beg = __builtin_amdgcn_readfirstlane(rowptr[n]);
  const int end = __builtin_amdgcn_readfirstlane(rowptr[n + 1]);
  float a0 = 0.f, a1 = 0.f, a2 = 0.f, a3 = 0.f,
        a4 = 0.f, a5 = 0.f, a6 = 0.f, a7 = 0.f;
  int e = beg;
  for (; e + 8 <= end; e += 8) {                   // 8 scalar edges, 8 chains
    const int2 q0 = edge[e],     q1 = edge[e + 1];
    const int2 q2 = edge[e + 2], q3 = edge[e + 3];
    const int2 q4 = edge[e + 4], q5 = edge[e + 5];
    const int2 q6 = edge[e + 6], q7 = edge[e + 7];
    a0 = fmaf(h[(size_t)q0.x * ND + lane], __int_as_float(q0.y), a0);
    a1 = fmaf(h[(size_t)q1.x * ND + lane], __int_as_float(q1.y), a1);
    a2 = fmaf(h[(size_t)q2.x * ND + lane], __int_as_float(q2.y), a2);
    a3 = fmaf(h[(size_t)q3.x * ND + lane], __int_as_float(q3.y), a3);
    a4 = fmaf(h[(size_t)q4.x * ND + lane], __int_as_float(q4.y), a4);
    a5 = fmaf(h[(size_t)q5.x * ND + lane], __int_as_float(q5.y), a5);
    a6 = fmaf(h[(size_t)q6.x * ND + lane], __int_as_float(q6.y), a6);
    a7 = fmaf(h[(size_t)q7.x * ND + lane], __int_as_float(q7.y), a7);
  }
  for (; e + 4 <= end; e += 4) {
    const int2 q0 = edge[e],     q1 = edge[e + 1];
    const int2 q2 = edge[e + 2], q3 = edge[e + 3];
    a0 = fmaf(h[(size_t)q0.x * ND + lane], __int_as_float(q0.y), a0);
    a1 = fmaf(h[(size_t)q1.x * ND + lane], __int_as_float(q1.y), a1);
    a2 = fmaf(h[(size_t)q2.x * ND + lane], __int_as_float(q2.y), a2);
    a3 = fmaf(h[(size_t)q3.x * ND + lane], __int_as_float(q3.y), a3);
  }
  for (; e < end; ++e) {
    const int2 q = edge[e];
    a0 = fmaf(h[(size_t)q.x * ND + lane], __int_as_float(q.y), a0);
  }
  const float dn = dis[n];
  const float hn = h[(size_t)n * ND + lane];       // = dis[n]*h_raw[n]
  float vv = fmaf((((a0 + a1) + (a2 + a3)) + ((a4 + a5) + (a6 + a7))) + hn,
                  dn, b1[lane]);
  vls[wid * 64 + lane] = fmaxf(vv, 0.0f);
  __syncthreads();
  if (wid == 0) {                                  // 4x64 @ 64x10 via MFMA
    const int lr = lane & 15, lg = lane >> 4;
    const v8s* bfr = (const v8s*)w2f + (size_t)lane * 2;
    v4f acc = (v4f){0.f, 0.f, 0.f, 0.f};
#pragma unroll
    for (int s = 0; s < 2; ++s) {
      v8s ah, al;
#pragma unroll
      for (int k = 0; k < 8; ++k) {
        float xv = vls[(lr & 3) * 64 + s * 32 + lg * 8 + k];
        xv = (lr < 4) ? xv : 0.0f;                 // rows 4..15 zero
        const unsigned short hb = bf16_rne(xv);
        ah[k] = (short)hb;
        al[k] = (short)bf16_rne(xv - __uint_as_float((unsigned int)hb << 16));
      }
      const v8s bh = bfr[s * 128], bl = bfr[s * 128 + 1];
      acc = __builtin_amdgcn_mfma_f32_16x16x32_bf16(ah, bh, acc, 0, 0, 0);
      acc = __builtin_amdgcn_mfma_f32_16x16x32_bf16(ah, bl, acc, 0, 0, 0);
      acc = __builtin_amdgcn_mfma_f32_16x16x32_bf16(al, bh, acc, 0, 0, 0);
    }
    if (lane < NC) {                               // col=lane, rows 0..3 = nodes
      const float bb = b2[lane];
#pragma unroll
      for (int r = 0; r < 4; ++r)
        out[(size_t)(blockIdx.x * 4 + r) * NC + lane] = acc[r] + bb;
    }
  }
}

extern "C" void kernel_launch(void* const* d_in, const int* in_sizes, int n_in,
                              void* d_out, int out_size, void* d_ws, size_t ws_size,
                              hipStream_t stream) {
  const float* x  = (const float*)d_in[0];
  const int*   ei = (const int*)d_in[1];   // (2, NE) row-major int32
  const float* ew = (const float*)d_in[2];
  const float* W1 = (const float*)d_in[3];
  const float* M1 = (const float*)d_in[4];
  const float* b1 = (const float*)d_in[5];
  const float* W2 = (const float*)d_in[6];
  const float* M2 = (const float*)d_in[7];
  const float* b2 = (const float*)d_in[8];
  float* out = (float*)d_out;
  float* ws  = (float*)d_ws;
  int*   wsi = (int*)d_ws;
  const int* src = ei;
  const int* dst = ei + NE;
  int2* buck = (int2*)(ws + OFF_H);        // aliases h, consumed pre-gemm1
  int2* edge = (int2*)(wsi + OFF_EDGE);
  int*  GH   = wsi + OFF_GH;
  int*  T    = wsi + OFF_BSUM;
  int*  TS   = wsi + OFF_BSUM + 256;

  prep_kernel<<<128, 256, 0, stream>>>(W1, M1, W2, M2, ws);
  part_hist<<<NPB, 256, 0, stream>>>(dst, GH);
  part_scan<<<NBUCK, 512, 0, stream>>>(GH, T);
  part_scan_t<<<1, 256, 0, stream>>>(T, TS);
  part_scatter<<<NPB, 256, 0, stream>>>(src, dst, ew, GH, TS, buck);
  bucket_sort<<<NBUCK, 512, 0, stream>>>(TS, buck, edge, wsi + OFF_RP,
                                         ws + OFF_DIS);
  gemm1_kernel<<<(NN + 127) / 128, 256, 0, stream>>>(x, ws + OFF_W1,
                                                     ws + OFF_DIS, ws + OFF_H);
  gather_kernel<<<NN / 4, 256, 0, stream>>>(wsi + OFF_RP, edge, ws + OFF_H,
                                            ws + OFF_DIS, b1, ws + OFF_W2F, b2, out);
}

// Round 8
// 559.613 us; speedup vs baseline: 1.0451x; 1.0451x over previous
//
#include <hip/hip_runtime.h>

#define NN 100000
#define NE 3200000
#define NF 512
#define ND 64
#define NC 10

#define NBUCK 196         // coarse buckets: dst>>9  (99999>>9 = 195)
#define NPB 500           // partition blocks
#define EPB 6400          // edges per partition block (NE/NPB)

// workspace layout (4-byte elements)
#define OFF_H      0          // NN*ND  h' = dis*(x @ W1eff); buck[] aliases (NE int2)
#define OFF_DIS    6400000    // NN     deg^-1/2 (written by bucket_sort)
#define OFF_W1     6500000    // NF*ND floats = 128KB: B-fragment array (bf16 hi/lo)
#define OFF_GH     6533408    // NBUCK*NPB = 98000 ints: per-(bin,block) histogram
#define OFF_RP     6633408    // NN+1   int CSR rowptr
#define OFF_BSUM   6733409    // 512 ints: T at +0, TS (197) at +256
#define OFF_EDGE   6733922    // NE int2 {src, bits(w)}  (8B-aligned)
#define OFF_W2F    13133922   // 1024 floats: W2eff bf16 hi/lo frags (64x16, zero-pad)
// total = 13,134,946 * 4B = 52.54 MB

typedef __attribute__((ext_vector_type(8))) short v8s;   // 8 bf16 = 4 VGPRs
typedef __attribute__((ext_vector_type(4))) float v4f;

// round-to-nearest-even fp32 -> bf16 (upper 16 bits)
__device__ __forceinline__ unsigned short bf16_rne(float f) {
  unsigned int u = __float_as_uint(f);
  return (unsigned short)((u + 0x7fffu + ((u >> 16) & 1u)) >> 16);
}

// W1eff and W2eff pre-split into bf16 hi/lo MFMA B-fragments.
// Fragment layout (MUST match the consumers):
//   k-step s = k>>5, lane-group g = (k>>3)&3, elem e = k&7, tile t = col>>4,
//   lane = (g<<4)|(col&15).  Halfword offset ((s*T+t)*64+lane)*16 + e (hi), +8 (lo).
// A and B use the SAME k->(g,e) mapping, so the MFMA result is invariant to
// the hardware's internal k-order (any consistent k-permutation cancels).
__global__ __launch_bounds__(256) void prep_kernel(
    const float* __restrict__ W1, const float* __restrict__ M1,
    const float* __restrict__ W2, const float* __restrict__ M2,
    float* __restrict__ ws) {
  const int i = blockIdx.x * 256 + threadIdx.x;   // grid = 128 (covers NF*ND)
  if (i < NF * ND) {
    const float v = W1[i] * M1[i];
    const int k = i >> 6, d = i & 63;             // i = k*ND + d
    const int s = k >> 5, g = (k >> 3) & 3, e = k & 7;
    const int t = d >> 4;
    const int lane = (g << 4) | (d & 15);
    unsigned short* bp = (unsigned short*)(ws + OFF_W1);
    const int base = ((s * 4 + t) * 64 + lane) * 16 + e;
    const unsigned short hb = bf16_rne(v);
    bp[base] = hb;
    bp[base + 8] = bf16_rne(v - __uint_as_float((unsigned int)hb << 16));
  }
  if (i < ND * 16) {                              // W2 frags, cols 10..15 zero
    const int k = i >> 4, c = i & 15;
    const float v = (c < NC) ? W2[k * NC + c] * M2[k * NC + c] : 0.0f;
    const int s = k >> 5, g = (k >> 3) & 3, e = k & 7;
    const int lane = (g << 4) | c;
    unsigned short* bp = (unsigned short*)(ws + OFF_W2F);
    const int base = (s * 64 + lane) * 16 + e;
    const unsigned short hb = bf16_rne(v);
    bp[base] = hb;
    bp[base + 8] = bf16_rne(v - __uint_as_float((unsigned int)hb << 16));
  }
}

// ---- CSR build: two-level counting sort, ZERO global atomics ----

// Pass A1: per-block coarse histogram (196 bins) via LDS atomics.
__global__ __launch_bounds__(256) void part_hist(
    const int* __restrict__ dst, int* __restrict__ GH) {
  __shared__ int hist[NBUCK];
  const int tid = threadIdx.x;
  for (int i = tid; i < NBUCK; i += 256) hist[i] = 0;
  __syncthreads();
  const int s0 = blockIdx.x * EPB;
  for (int e = s0 + tid; e < s0 + EPB; e += 256)
    atomicAdd(&hist[dst[e] >> 9], 1);
  __syncthreads();
  for (int i = tid; i < NBUCK; i += 256)
    GH[i * NPB + blockIdx.x] = hist[i];            // bin-major for the scan
}

// Pass A2: per-bin exclusive scan over the NPB block counts (in place),
// bin totals to T.
__global__ __launch_bounds__(512) void part_scan(
    int* __restrict__ GH, int* __restrict__ T) {
  __shared__ int s[512];
  const int t = threadIdx.x;
  const int b = blockIdx.x;                        // bin
  const int v = (t < NPB) ? GH[b * NPB + t] : 0;
  s[t] = v; __syncthreads();
  for (int off = 1; off < 512; off <<= 1) {
    const int a = (t >= off) ? s[t - off] : 0;
    __syncthreads();
    s[t] += a;
    __syncthreads();
  }
  if (t < NPB) GH[b * NPB + t] = s[t] - v;         // exclusive within bin
  if (t == 511) T[b] = s[511];                     // bin total
}

// Pass A3: exclusive scan of the 196 bin totals -> TS (+ sentinel TS[196]=NE).
__global__ __launch_bounds__(256) void part_scan_t(
    const int* __restrict__ T, int* __restrict__ TS) {
  __shared__ int s[256];
  const int t = threadIdx.x;
  const int v = (t < NBUCK) ? T[t] : 0;
  s[t] = v; __syncthreads();
  for (int off = 1; off < 256; off <<= 1) {
    const int a = (t >= off) ? s[t - off] : 0;
    __syncthreads();
    s[t] += a;
    __syncthreads();
  }
  if (t < NBUCK) TS[t] = s[t] - v;
  if (t == NBUCK - 1) TS[NBUCK] = s[t];            // == NE
}

// Pass A4: scatter edges into coarse-bucket runs.  Each block's range within
// each bucket is exclusive (prefix-scanned), rank via LDS cursor.
// Pack: src (17b) | fine-dst (9b) << 17;  w as float bits.
__global__ __launch_bounds__(256) void part_scatter(
    const int* __restrict__ src, const int* __restrict__ dst,
    const float* __restrict__ ew, const int* __restrict__ GH,
    const int* __restrict__ TS, int2* __restrict__ buck) {
  __shared__ int cursor[NBUCK];
  const int tid = threadIdx.x;
  for (int i = tid; i < NBUCK; i += 256)
    cursor[i] = GH[i * NPB + blockIdx.x] + TS[i];
  __syncthreads();
  const int s0 = blockIdx.x * EPB;
  for (int e = s0 + tid; e < s0 + EPB; e += 256) {
    const int d = dst[e];
    const int pos = atomicAdd(&cursor[d >> 9], 1);
    buck[pos] = make_int2(src[e] | ((d & 511) << 17), __float_as_int(ew[e]));
  }
}

// Pass B: one block per coarse bucket (512 fine bins = 512 nodes).
// Read 1: fine histogram + weighted-degree (both LDS atomics, same read).
// In-block scan -> rowptr + dis.  Read 2: scatter to final CSR edge array.
__global__ __launch_bounds__(512) void bucket_sort(
    const int* __restrict__ TS, const int2* __restrict__ buck,
    int2* __restrict__ edge, int* __restrict__ rowptr,
    float* __restrict__ dis) {
  __shared__ int hist[512];
  __shared__ float deg[512];
  __shared__ int scn[512];
  const int t = threadIdx.x;
  const int b = blockIdx.x;
  const int beg = TS[b], endd = TS[b + 1];
  hist[t] = 0; deg[t] = 0.0f;
  __syncthreads();
  for (int e = beg + t; e < endd; e += 512) {
    const int2 q = buck[e];
    const int fine = (q.x >> 17) & 511;
    atomicAdd(&hist[fine], 1);
    atomicAdd(&deg[fine], __int_as_float(q.y));
  }
  __syncthreads();
  const int sv = hist[t];
  scn[t] = sv; __syncthreads();
  for (int off = 1; off < 512; off <<= 1) {
    const int a = (t >= off) ? scn[t - off] : 0;
    __syncthreads();
    scn[t] += a;
    __syncthreads();
  }
  const int ex = scn[t] - sv;                      // exclusive
  const int node = b * 512 + t;
  if (node < NN) {
    rowptr[node] = beg + ex;
    dis[node] = rsqrtf(deg[t] + 1.0f);             // +1 = self-loop weight
  }
  if (b == NBUCK - 1 && t == 0) rowptr[NN] = endd; // == NE
  hist[t] = beg + ex;                              // reuse hist as cursor
  __syncthreads();
  for (int e = beg + t; e < endd; e += 512) {
    const int2 q = buck[e];
    const int fine = (q.x >> 17) & 511;
    const int pos = atomicAdd(&hist[fine], 1);
    edge[pos] = make_int2(q.x & 0x1FFFF, q.y);
  }
}

// h' = dis * (x @ Weff1) via bf16-split MFMA (xh*wh + xh*wl + xl*wh, fp32 acc).
// Latency-structured version (R7 post-mortem: 2-barrier/step + 1-step
// prefetch + 782-block grid was latency-bound at 23% occupancy):
//   - 64-row tiles -> 1563 blocks (6/CU), LDS 2x8KB (10 blocks/CU possible)
//   - 2-step-deep register prefetch (pfA/pfB, static names): load->use slack
//     = 2 compute phases (~800cy) >= HBM miss latency
//   - ONE barrier per k-step: with double-buffered LDS, write(xs[p], s)
//     conflicts only with reads at s-2, and the s-1 barrier orders those.
//   - staging & fragment reads both exactly 8 words/bank (wave64 minimum)
//     via unit-XOR swizzle (unit ^= row&7, 16B units in each 128B row).
// C layout (m89-verified): col = lane&15, row = (lane>>4)*4 + reg.
__global__ __launch_bounds__(256) void gemm1_kernel(
    const float* __restrict__ x, const float* __restrict__ bfrag_f,
    const float* __restrict__ dis, float* __restrict__ h) {
  __shared__ __align__(16) float xs[2][64 * 32];   // 2 x 8 KB
  const int tid  = threadIdx.x;
  const int lane = tid & 63;
  const int wid  = tid >> 6;
  const size_t brow = (size_t)blockIdx.x * 64;
  // staging: thread t -> row t>>2, two 16B units starting at (t&3)*2
  const int srow = tid >> 2;
  const int u0   = (tid & 3) * 2;
  const int sr7  = srow & 7;
  size_t grow = brow + srow;
  if (grow >= NN) grow = NN - 1;                   // clamp (no early return)
  const float* gx = x + grow * NF + u0 * 4;

  const int lr = lane & 15;               // A row / B col / C col within tile
  const int lg = lane >> 4;               // k-group
  const size_t row0 = brow + (size_t)wid * 16;     // wave's 16 rows
  const int rl = wid * 16 + lr;                    // row within slab
  const int r7 = rl & 7;
  const v8s* bfr = (const v8s*)bfrag_f + (size_t)lane * 2;  // 32B per lane
  v4f acc[4];
#pragma unroll
  for (int t = 0; t < 4; ++t) acc[t] = (v4f){0.f, 0.f, 0.f, 0.f};

  // prefetch steps 0 and 1
  float4 pA0 = *(const float4*)(gx);
  float4 pA1 = *(const float4*)(gx + 4);
  float4 pB0 = *(const float4*)(gx + 32);
  float4 pB1 = *(const float4*)(gx + 36);

  for (int ss = 0; ss < 8; ++ss) {
    // ---- even step s = 2*ss, buffer 0, pfA ----
    {
      float* wr = &xs[0][srow * 32];
      *(float4*)(wr + ((u0 ^ sr7) << 2))       = pA0;
      *(float4*)(wr + (((u0 + 1) ^ sr7) << 2)) = pA1;
      if (ss < 7) {                                // load step s+2
        const float* g2 = gx + (2 * ss + 2) * 32;
        pA0 = *(const float4*)(g2);
        pA1 = *(const float4*)(g2 + 4);
      }
      __syncthreads();
      const float* rp = &xs[0][rl * 32];
      const float4 p0 = *(const float4*)(rp + (((lg * 2) ^ r7) << 2));
      const float4 p1 = *(const float4*)(rp + (((lg * 2 + 1) ^ r7) << 2));
      const float vv[8] = {p0.x, p0.y, p0.z, p0.w, p1.x, p1.y, p1.z, p1.w};
      v8s ah, al;
#pragma unroll
      for (int e = 0; e < 8; ++e) {
        const unsigned short hb = bf16_rne(vv[e]);
        ah[e] = (short)hb;
        al[e] = (short)bf16_rne(vv[e] - __uint_as_float((unsigned int)hb << 16));
      }
      const int s = 2 * ss;
#pragma unroll
      for (int t = 0; t < 4; ++t) {
        const v8s bh = bfr[(size_t)(s * 4 + t) * 128];
        const v8s bl = bfr[(size_t)(s * 4 + t) * 128 + 1];
        acc[t] = __builtin_amdgcn_mfma_f32_16x16x32_bf16(ah, bh, acc[t], 0, 0, 0);
        acc[t] = __builtin_amdgcn_mfma_f32_16x16x32_bf16(ah, bl, acc[t], 0, 0, 0);
        acc[t] = __builtin_amdgcn_mfma_f32_16x16x32_bf16(al, bh, acc[t], 0, 0, 0);
      }
    }
    // ---- odd step s = 2*ss+1, buffer 1, pfB ----
    {
      float* wr = &xs[1][srow * 32];
      *(float4*)(wr + ((u0 ^ sr7) << 2))       = pB0;
      *(float4*)(wr + (((u0 + 1) ^ sr7) << 2)) = pB1;
      if (ss < 7) {                                // load step s+2
        const float* g2 = gx + (2 * ss + 3) * 32;
        pB0 = *(const float4*)(g2);
        pB1 = *(const float4*)(g2 + 4);
      }
      __syncthreads();
      const float* rp = &xs[1][rl * 32];
      const float4 p0 = *(const float4*)(rp + (((lg * 2) ^ r7) << 2));
      const float4 p1 = *(const float4*)(rp + (((lg * 2 + 1) ^ r7) << 2));
      const float vv[8] = {p0.x, p0.y, p0.z, p0.w, p1.x, p1.y, p1.z, p1.w};
      v8s ah, al;
#pragma unroll
      for (int e = 0; e < 8; ++e) {
        const unsigned short hb = bf16_rne(vv[e]);
        ah[e] = (short)hb;
        al[e] = (short)bf16_rne(vv[e] - __uint_as_float((unsigned int)hb << 16));
      }
      const int s = 2 * ss + 1;
#pragma unroll
      for (int t = 0; t < 4; ++t) {
        const v8s bh = bfr[(size_t)(s * 4 + t) * 128];
        const v8s bl = bfr[(size_t)(s * 4 + t) * 128 + 1];
        acc[t] = __builtin_amdgcn_mfma_f32_16x16x32_bf16(ah, bh, acc[t], 0, 0, 0);
        acc[t] = __builtin_amdgcn_mfma_f32_16x16x32_bf16(ah, bl, acc[t], 0, 0, 0);
        acc[t] = __builtin_amdgcn_mfma_f32_16x16x32_bf16(al, bh, acc[t], 0, 0, 0);
      }
    }
  }
  if (row0 < NN) {                                 // NN%16==0: wave all-or-none
#pragma unroll
    for (int r = 0; r < 4; ++r) {
      const size_t row = row0 + lg * 4 + r;
      const float dv = dis[row];          // 16-lane broadcast, L1-resident
#pragma unroll
      for (int t = 0; t < 4; ++t)
        h[row * ND + t * 16 + lr] = acc[t][r] * dv;
    }
  }
}

// One wave per dst node.  Edge list is wave-uniform -> scalar s_load stream;
// h' already carries dis[src], so the inner loop is 1 scalar edge read +
// 1 coalesced 256B h-row load + 1 v_fmac (SGPR multiplier) per edge,
// 8 independent chains.  Epilogue: out = dis[n]*(sum + h'[n]) + b1, ReLU,
// then 4 waves stage rows in LDS and wave 0 runs the 64x10 classifier as
// one bf16-split MFMA tile.
__global__ __launch_bounds__(256) void gather_kernel(
    const int* __restrict__ rowptr, const int2* __restrict__ edge,
    const float* __restrict__ h, const float* __restrict__ dis,
    const float* __restrict__ b1, const float* __restrict__ w2f,
    const float* __restrict__ b2, float* __restrict__ out) {
  __shared__ float vls[4 * 64];
  const int lane = threadIdx.x & 63;
  const int wid  = threadIdx.x >> 6;
  const int n = blockIdx.x * 4 + wid;              // grid exact: n < NN
  const int beg = __builtin_amdgcn_readfirstlane(rowptr[n]);
  const int end = __builtin_amdgcn_readfirstlane(rowptr[n + 1]);
  float a0 = 0.f, a1 = 0.f, a2 = 0.f, a3 = 0.f,
        a4 = 0.f, a5 = 0.f, a6 = 0.f, a7 = 0.f;
  int e = beg;
  for (; e + 8 <= end; e += 8) {                   // 8 scalar edges, 8 chains
    const int2 q0 = edge[e],     q1 = edge[e + 1];
    const int2 q2 = edge[e + 2], q3 = edge[e + 3];
    const int2 q4 = edge[e + 4], q5 = edge[e + 5];
    const int2 q6 = edge[e + 6], q7 = edge[e + 7];
    a0 = fmaf(h[(size_t)q0.x * ND + lane], __int_as_float(q0.y), a0);
    a1 = fmaf(h[(size_t)q1.x * ND + lane], __int_as_float(q1.y), a1);
    a2 = fmaf(h[(size_t)q2.x * ND + lane], __int_as_float(q2.y), a2);
    a3 = fmaf(h[(size_t)q3.x * ND + lane], __int_as_float(q3.y), a3);
    a4 = fmaf(h[(size_t)q4.x * ND + lane], __int_as_float(q4.y), a4);
    a5 = fmaf(h[(size_t)q5.x * ND + lane], __int_as_float(q5.y), a5);
    a6 = fmaf(h[(size_t)q6.x * ND + lane], __int_as_float(q6.y), a6);
    a7 = fmaf(h[(size_t)q7.x * ND + lane], __int_as_float(q7.y), a7);
  }
  for (; e + 4 <= end; e += 4) {
    const int2 q0 = edge[e],     q1 = edge[e + 1];
    const int2 q2 = edge[e + 2], q3 = edge[e + 3];
    a0 = fmaf(h[(size_t)q0.x * ND + lane], __int_as_float(q0.y), a0);
    a1 = fmaf(h[(size_t)q1.x * ND + lane], __int_as_float(q1.y), a1);
    a2 = fmaf(h[(size_t)q2.x * ND + lane], __int_as_float(q2.y), a2);
    a3 = fmaf(h[(size_t)q3.x * ND + lane], __int_as_float(q3.y), a3);
  }
  for (; e < end; ++e) {
    const int2 q = edge[e];
    a0 = fmaf(h[(size_t)q.x * ND + lane], __int_as_float(q.y), a0);
  }
  const float dn = dis[n];
  const float hn = h[(size_t)n * ND + lane];       // = dis[n]*h_raw[n]
  float vv = fmaf((((a0 + a1) + (a2 + a3)) + ((a4 + a5) + (a6 + a7))) + hn,
                  dn, b1[lane]);
  vls[wid * 64 + lane] = fmaxf(vv, 0.0f);
  __syncthreads();
  if (wid == 0) {                                  // 4x64 @ 64x10 via MFMA
    const int lr = lane & 15, lg = lane >> 4;
    const v8s* bfr = (const v8s*)w2f + (size_t)lane * 2;
    v4f acc = (v4f){0.f, 0.f, 0.f, 0.f};
#pragma unroll
    for (int s = 0; s < 2; ++s) {
      v8s ah, al;
#pragma unroll
      for (int k = 0; k < 8; ++k) {
        float xv = vls[(lr & 3) * 64 + s * 32 + lg * 8 + k];
        xv = (lr < 4) ? xv : 0.0f;                 // rows 4..15 zero
        const unsigned short hb = bf16_rne(xv);
        ah[k] = (short)hb;
        al[k] = (short)bf16_rne(xv - __uint_as_float((unsigned int)hb << 16));
      }
      const v8s bh = bfr[s * 128], bl = bfr[s * 128 + 1];
      acc = __builtin_amdgcn_mfma_f32_16x16x32_bf16(ah, bh, acc, 0, 0, 0);
      acc = __builtin_amdgcn_mfma_f32_16x16x32_bf16(ah, bl, acc, 0, 0, 0);
      acc = __builtin_amdgcn_mfma_f32_16x16x32_bf16(al, bh, acc, 0, 0, 0);
    }
    if (lane < NC) {                               // col=lane, rows 0..3 = nodes
      const float bb = b2[lane];
#pragma unroll
      for (int r = 0; r < 4; ++r)
        out[(size_t)(blockIdx.x * 4 + r) * NC + lane] = acc[r] + bb;
    }
  }
}

extern "C" void kernel_launch(void* const* d_in, const int* in_sizes, int n_in,
                              void* d_out, int out_size, void* d_ws, size_t ws_size,
                              hipStream_t stream) {
  const float* x  = (const float*)d_in[0];
  const int*   ei = (const int*)d_in[1];   // (2, NE) row-major int32
  const float* ew = (const float*)d_in[2];
  const float* W1 = (const float*)d_in[3];
  const float* M1 = (const float*)d_in[4];
  const float* b1 = (const float*)d_in[5];
  const float* W2 = (const float*)d_in[6];
  const float* M2 = (const float*)d_in[7];
  const float* b2 = (const float*)d_in[8];
  float* out = (float*)d_out;
  float* ws  = (float*)d_ws;
  int*   wsi = (int*)d_ws;
  const int* src = ei;
  const int* dst = ei + NE;
  int2* buck = (int2*)(ws + OFF_H);        // aliases h, consumed pre-gemm1
  int2* edge = (int2*)(wsi + OFF_EDGE);
  int*  GH   = wsi + OFF_GH;
  int*  T    = wsi + OFF_BSUM;
  int*  TS   = wsi + OFF_BSUM + 256;

  prep_kernel<<<128, 256, 0, stream>>>(W1, M1, W2, M2, ws);
  part_hist<<<NPB, 256, 0, stream>>>(dst, GH);
  part_scan<<<NBUCK, 512, 0, stream>>>(GH, T);
  part_scan_t<<<1, 256, 0, stream>>>(T, TS);
  part_scatter<<<NPB, 256, 0, stream>>>(src, dst, ew, GH, TS, buck);
  bucket_sort<<<NBUCK, 512, 0, stream>>>(TS, buck, edge, wsi + OFF_RP,
                                         ws + OFF_DIS);
  gemm1_kernel<<<(NN + 63) / 64, 256, 0, stream>>>(x, ws + OFF_W1,
                                                   ws + OFF_DIS, ws + OFF_H);
  gather_kernel<<<NN / 4, 256, 0, stream>>>(wsi + OFF_RP, edge, ws + OFF_H,
                                            ws + OFF_DIS, b1, ws + OFF_W2F, b2, out);
}